// Round 14
// baseline (310.265 us; speedup 1.0000x reference)
//
#include <hip/hip_runtime.h>

#define N_NODES 50000
#define N_EDGES 800000
#define D1 64
#define D2 32
#define N_CLASSES 6
#define N_GRAPHS 128
#define CAP 64       // per-node src bucket capacity == wave size; deg max ~45 << 64
#define GB 782       // ceil(50000/64) for 16x16 mm tiles
#define GRB 391      // ceil(50000/128) for 32-row-per-wave gru blocks
#define NFB 3125     // N_EDGES/256 fill blocks

typedef unsigned short u16;
typedef unsigned int u32;
typedef __attribute__((ext_vector_type(8))) short bf16x8;
typedef __attribute__((ext_vector_type(4))) float f32x4;
typedef __attribute__((ext_vector_type(16))) float f32x16;

__device__ __forceinline__ float bf2f(u16 b) {
    u32 u = ((u32)b) << 16;
    float f;
    __builtin_memcpy(&f, &u, 4);
    return f;
}
__device__ __forceinline__ u16 f2bf(float f) {
    u32 u;
    __builtin_memcpy(&u, &f, 4);
    u32 r = (u + 0x7fffu + ((u >> 16) & 1u)) >> 16;
    return (u16)r;
}
__device__ __forceinline__ void split8(const float* v, bf16x8& hi, bf16x8& lo) {
#pragma unroll
    for (int j = 0; j < 8; ++j) {
        u16 h = f2bf(v[j]);
        hi[j] = (short)h;
        lo[j] = (short)f2bf(v[j] - bf2f(h));
    }
}
__device__ __forceinline__ float sigmoidf_(float x) {
    return 1.0f / (1.0f + __expf(-x));
}
__device__ __forceinline__ float tanhf_(float x) {
    return 1.0f - 2.0f / (__expf(2.0f * x) + 1.0f);
}

// ===== fused: fill + pack + mm L0, interleaved in block-index space =====
// period-13 groups: 10 fill + 3 other (r12 lesson: consecutive ranges queue serially).
// B packed for 32x32x16 fragments: idx=(kt*8+nt)*512+lane*8+j,
//   value=Blog[k=kt*16+(lane>>5)*8+j][n=nt*32+(lane&31)], kt,nt in 0..7.
__global__ __launch_bounds__(256) void fused_head_kernel(
        const int* __restrict__ ei, int* __restrict__ deg, u16* __restrict__ srcidx,
        const float* __restrict__ x, const float* __restrict__ W,
        const float* __restrict__ wih, const float* __restrict__ whh,
        const float* __restrict__ bih, const float* __restrict__ bhh,
        short* __restrict__ Bh, short* __restrict__ Bl, float* __restrict__ bias4,
        u16* __restrict__ m16) {
    int b = blockIdx.x;
    int tid = threadIdx.x;
    int grp = b / 13, rem = b % 13;
    if (rem < 10) {
        // ---- bucketed fill: one edge per thread (deg pre-zeroed via memset) ----
        int fb = grp * 10 + rem;
        if (fb >= NFB) return;
        int e = fb * 256 + tid;
        int d = ei[N_EDGES + e];
        int s = ei[e];
        int p = atomicAdd(&deg[d], 1);
        if (p < CAP) srcidx[d * CAP + p] = (u16)s;
        return;
    }
    int ob = grp * 3 + (rem - 10);  // 128 pack + 1 bias + 782 mm = 911 used
    if (ob < 128) {
        // ---- pack GRU B in 32x32x16 fragment order ----
        int idx = ob * 256 + tid;
        int j = idx & 7;
        int lane = (idx >> 3) & 63;
        int nt = (idx >> 9) & 7;
        int kt = idx >> 12;
        int k = kt * 16 + (lane >> 5) * 8 + j;
        int n = nt * 32 + (lane & 31);
        int g = n >> 6, d = n & 63;
        float v;
        if (g == 0)      v = (k < 64) ? wih[d * 64 + k] : whh[d * 64 + (k - 64)];
        else if (g == 1) v = (k < 64) ? wih[(64 + d) * 64 + k] : whh[(64 + d) * 64 + (k - 64)];
        else if (g == 2) v = (k < 64) ? wih[(128 + d) * 64 + k] : 0.f;
        else             v = (k < 64) ? 0.f : whh[(128 + d) * 64 + (k - 64)];
        u16 hi = f2bf(v);
        Bh[idx] = (short)hi;
        Bl[idx] = (short)f2bf(v - bf2f(hi));
    } else if (ob == 128) {
        int j = tid;
        if (j < 64) {
            bias4[j] = bih[j] + bhh[j];
            bias4[64 + j] = bih[64 + j] + bhh[64 + j];
            bias4[128 + j] = bih[128 + j];
            bias4[192 + j] = bhh[128 + j];
        }
    } else if (ob < 129 + GB) {
        // ---- mm L0: m = x @ W0, raw f32 W (16 KB, L1-resident), split in-register ----
        int lane = tid & 63;
        int wv = tid >> 6;
        int node0 = (ob - 129) * 64 + wv * 16;
        if (node0 >= N_NODES) return;
        int c0 = lane & 15, qr = lane >> 4;
        f32x4 acc[4];
#pragma unroll
        for (int nt = 0; nt < 4; ++nt) acc[nt] = (f32x4){0.f, 0.f, 0.f, 0.f};
#pragma unroll
        for (int kt = 0; kt < 2; ++kt) {
            int aoff = (node0 + c0) * 64 + kt * 32 + qr * 8;
            float tmp[8];
#pragma unroll
            for (int j = 0; j < 8; ++j) tmp[j] = x[aoff + j];
            bf16x8 ah, al;
            split8(tmp, ah, al);
            int k0 = kt * 32 + qr * 8;
#pragma unroll
            for (int nt = 0; nt < 4; ++nt) {
                int n = nt * 16 + c0;
                float wt[8];
#pragma unroll
                for (int j = 0; j < 8; ++j) wt[j] = W[(k0 + j) * 64 + n];
                bf16x8 bh, bl;
                split8(wt, bh, bl);
                acc[nt] = __builtin_amdgcn_mfma_f32_16x16x32_bf16(ah, bh, acc[nt], 0, 0, 0);
                acc[nt] = __builtin_amdgcn_mfma_f32_16x16x32_bf16(ah, bl, acc[nt], 0, 0, 0);
                acc[nt] = __builtin_amdgcn_mfma_f32_16x16x32_bf16(al, bh, acc[nt], 0, 0, 0);
            }
        }
#pragma unroll
        for (int nt = 0; nt < 4; ++nt)
#pragma unroll
            for (int r = 0; r < 4; ++r)
                m16[(node0 + qr * 4 + r) * 64 + nt * 16 + c0] = f2bf(acc[nt][r]);
    }
}

// ===== mm L1: m = h @ W1 (16x16), A from hhi/hlo, raw f32 W =====
__global__ __launch_bounds__(256) void mm_mfma(const short* __restrict__ Ahi,
                                               const short* __restrict__ Alo,
                                               const float* __restrict__ Wf,
                                               u16* __restrict__ m16) {
    int lane = threadIdx.x & 63;
    int wv = threadIdx.x >> 6;
    int node0 = blockIdx.x * 64 + wv * 16;
    if (node0 >= N_NODES) return;
    int c0 = lane & 15, qr = lane >> 4;
    f32x4 acc[4];
#pragma unroll
    for (int nt = 0; nt < 4; ++nt) acc[nt] = (f32x4){0.f, 0.f, 0.f, 0.f};
#pragma unroll
    for (int kt = 0; kt < 2; ++kt) {
        int aoff = (node0 + c0) * 64 + kt * 32 + qr * 8;
        bf16x8 ah = *(const bf16x8*)(Ahi + aoff);
        bf16x8 al = *(const bf16x8*)(Alo + aoff);
        int k0 = kt * 32 + qr * 8;
#pragma unroll
        for (int nt = 0; nt < 4; ++nt) {
            int n = nt * 16 + c0;
            float wt[8];
#pragma unroll
            for (int j = 0; j < 8; ++j) wt[j] = Wf[(k0 + j) * 64 + n];
            bf16x8 bh, bl;
            split8(wt, bh, bl);
            acc[nt] = __builtin_amdgcn_mfma_f32_16x16x32_bf16(ah, bh, acc[nt], 0, 0, 0);
            acc[nt] = __builtin_amdgcn_mfma_f32_16x16x32_bf16(ah, bl, acc[nt], 0, 0, 0);
            acc[nt] = __builtin_amdgcn_mfma_f32_16x16x32_bf16(al, bh, acc[nt], 0, 0, 0);
        }
    }
#pragma unroll
    for (int nt = 0; nt < 4; ++nt)
#pragma unroll
        for (int r = 0; r < 4; ++r)
            m16[(node0 + qr * 4 + r) * 64 + nt * 16 + c0] = f2bf(acc[nt][r]);
}

// ===== agg: wave per node; half-wave dword gather =====
__global__ __launch_bounds__(256) void agg_kernel(const u16* __restrict__ m16,
                                                  const int* __restrict__ deg,
                                                  const u16* __restrict__ srcidx,
                                                  short* __restrict__ aghi,
                                                  short* __restrict__ aglo) {
    int lane = threadIdx.x & 63;
    int wv = threadIdx.x >> 6;
    int node = blockIdx.x * 4 + wv;  // grid exact: 50000/4
    int cnt = __builtin_amdgcn_readfirstlane(deg[node]);
    cnt = cnt < CAP ? cnt : CAP;
    int bv = (int)srcidx[node * CAP + lane];
    int half = lane >> 5;
    int l = lane & 31;
    const u32* m32 = (const u32*)m16;
    float a0 = 0.f, a1 = 0.f;
    int k = half;
    for (; k + 6 < cnt; k += 8) {
        int s0 = __shfl(bv, k);
        int s1 = __shfl(bv, k + 2);
        int s2 = __shfl(bv, k + 4);
        int s3 = __shfl(bv, k + 6);
        u32 d0 = m32[s0 * 32 + l];
        u32 d1 = m32[s1 * 32 + l];
        u32 d2 = m32[s2 * 32 + l];
        u32 d3 = m32[s3 * 32 + l];
        a0 += bf2f((u16)d0) + bf2f((u16)d1) + bf2f((u16)d2) + bf2f((u16)d3);
        a1 += bf2f((u16)(d0 >> 16)) + bf2f((u16)(d1 >> 16)) +
              bf2f((u16)(d2 >> 16)) + bf2f((u16)(d3 >> 16));
    }
    for (; k < cnt; k += 2) {
        int s = __shfl(bv, k);
        u32 d = m32[s * 32 + l];
        a0 += bf2f((u16)d);
        a1 += bf2f((u16)(d >> 16));
    }
    a0 += __shfl_xor(a0, 32);
    a1 += __shfl_xor(a1, 32);
    if (half == 0) {
        u16 h0 = f2bf(a0), h1 = f2bf(a1);
        u16 g0 = f2bf(a0 - bf2f(h0)), g1 = f2bf(a1 - bf2f(h1));
        ((u32*)aghi)[node * 32 + l] = (u32)h0 | ((u32)h1 << 16);
        ((u32*)aglo)[node * 32 + l] = (u32)g0 | ((u32)g1 << 16);
    }
}

// ===== GRU on 32x32x16 MFMA: wave = 32 rows; B direct from L2; no LDS, no barriers.
// A layout: m=lane&31, k=(lane>>5)*8+j. C/D: col=lane&31, row=(reg&3)+8*(reg>>2)+4*(lane>>5).
template <bool L0, bool LAST>
__global__ __launch_bounds__(256) void gru_mfma(const short* __restrict__ aghi,
                                                const short* __restrict__ aglo,
                                                short* hhi, short* hlo,
                                                const short* __restrict__ Bh,
                                                const short* __restrict__ Bl,
                                                const float* __restrict__ bias4,
                                                const float* __restrict__ hin,  // x (L0) or h f32
                                                float* __restrict__ hout) {
    int tid = threadIdx.x;
    int lane = tid & 63;
    int wv = tid >> 6;
    int node0 = blockIdx.x * 128 + wv * 32;
    if (node0 >= N_NODES) return;
    int c = lane & 31, half = lane >> 5;
    // clamp A-row address (last partial tile): results for rows >= N_NODES discarded
    int rowA = node0 + c;
    if (rowA > N_NODES - 1) rowA = N_NODES - 1;

    f32x16 acc[8];
#pragma unroll
    for (int nt = 0; nt < 8; ++nt)
#pragma unroll
        for (int i = 0; i < 16; ++i) acc[nt][i] = 0.f;

#pragma unroll
    for (int kt = 0; kt < 8; ++kt) {
        bf16x8 ah, al;
        int aoff = rowA * 64 + (kt & 3) * 16 + half * 8;
        if (kt < 4) {
            ah = *(const bf16x8*)(aghi + aoff);
            al = *(const bf16x8*)(aglo + aoff);
        } else if (L0) {  // h half = x, split in-register
            float tmp[8];
#pragma unroll
            for (int j = 0; j < 8; ++j) tmp[j] = hin[aoff + j];
            split8(tmp, ah, al);
        } else {
            ah = *(const bf16x8*)(hhi + aoff);
            al = *(const bf16x8*)(hlo + aoff);
        }
#pragma unroll
        for (int nt = 0; nt < 8; ++nt) {
            int boff = (kt * 8 + nt) * 512 + lane * 8;
            bf16x8 bh = *(const bf16x8*)(Bh + boff);
            bf16x8 bl = *(const bf16x8*)(Bl + boff);
            acc[nt] = __builtin_amdgcn_mfma_f32_32x32x16_bf16(ah, bh, acc[nt], 0, 0, 0);
            acc[nt] = __builtin_amdgcn_mfma_f32_32x32x16_bf16(ah, bl, acc[nt], 0, 0, 0);
            acc[nt] = __builtin_amdgcn_mfma_f32_32x32x16_bf16(al, bh, acc[nt], 0, 0, 0);
        }
    }

    // gates: col j=jt*32+c lives in nt {jt, 2+jt, 4+jt, 6+jt} (r, z, i_n, h_n)
#pragma unroll
    for (int reg = 0; reg < 16; ++reg) {
        int row = node0 + (reg & 3) + 8 * (reg >> 2) + 4 * half;
        if (row >= N_NODES) continue;
#pragma unroll
        for (int jt = 0; jt < 2; ++jt) {
            int j = jt * 32 + c;
            float rr = sigmoidf_(acc[jt][reg] + bias4[j]);
            float zz = sigmoidf_(acc[2 + jt][reg] + bias4[64 + j]);
            float nn = tanhf_(acc[4 + jt][reg] + bias4[128 + j] +
                              rr * (acc[6 + jt][reg] + bias4[192 + j]));
            float ho = hin[row * 64 + j];
            float v = (1.f - zz) * nn + zz * ho;
            hout[row * 64 + j] = v;
            if (!LAST) {
                u16 hi = f2bf(v);
                hhi[row * 64 + j] = (short)hi;
                hlo[row * 64 + j] = (short)f2bf(v - bf2f(hi));
            }
        }
    }
}

// ===== fused relu + segment-mean pool + fc1/relu/fc2/log_softmax; block per graph =====
__global__ __launch_bounds__(256) void poolhead_kernel(const float* __restrict__ h,
                                                       const int* __restrict__ batch,
                                                       const float* __restrict__ fc1w,
                                                       const float* __restrict__ fc1b,
                                                       const float* __restrict__ fc2w,
                                                       const float* __restrict__ fc2b,
                                                       float* __restrict__ out) {
    int g = blockIdx.x;
    int tid = threadIdx.x, lane = tid & 63, wv = tid >> 6;
    int lo, hi;
    {
        int a = 0, b = N_NODES;
        while (a < b) { int mid = (a + b) >> 1; if (batch[mid] < g) a = mid + 1; else b = mid; }
        lo = a;
    }
    {
        int a = lo, b = N_NODES;
        while (a < b) { int mid = (a + b) >> 1; if (batch[mid] < g + 1) a = mid + 1; else b = mid; }
        hi = a;
    }
    float acc = 0.f;
    for (int n = lo + wv; n < hi; n += 4) acc += fmaxf(h[n * 64 + lane], 0.f);
    __shared__ float red[4][64];
    __shared__ float pv[64];
    __shared__ float s1[32];
    __shared__ float s2[6];
    red[wv][lane] = acc;
    __syncthreads();
    if (tid < 64)
        pv[tid] = (red[0][tid] + red[1][tid] + red[2][tid] + red[3][tid]) /
                  fmaxf((float)(hi - lo), 1.f);
    __syncthreads();
    if (tid < 32) {
        float a2 = fc1b[tid];
#pragma unroll
        for (int j = 0; j < 64; ++j) a2 = fmaf(pv[j], fc1w[tid * 64 + j], a2);
        s1[tid] = fmaxf(a2, 0.f);
    }
    __syncthreads();
    if (tid < 6) {
        float a2 = fc2b[tid];
#pragma unroll
        for (int j = 0; j < 32; ++j) a2 = fmaf(s1[j], fc2w[tid * 32 + j], a2);
        s2[tid] = a2;
    }
    __syncthreads();
    if (tid == 0) {
        float mx = s2[0];
#pragma unroll
        for (int c = 1; c < 6; ++c) mx = fmaxf(mx, s2[c]);
        float se = 0.f;
#pragma unroll
        for (int c = 0; c < 6; ++c) se += __expf(s2[c] - mx);
        float lse = mx + __logf(se);
#pragma unroll
        for (int c = 0; c < 6; ++c) out[g * 6 + c] = s2[c] - lse;
    }
}

extern "C" void kernel_launch(void* const* d_in, const int* in_sizes, int n_in,
                              void* d_out, int out_size, void* d_ws, size_t ws_size,
                              hipStream_t stream) {
    const float* x    = (const float*)d_in[0];
    const int* ei     = (const int*)d_in[1];
    const int* batch  = (const int*)d_in[2];
    const float* W    = (const float*)d_in[3];
    const float* wih  = (const float*)d_in[4];
    const float* whh  = (const float*)d_in[5];
    const float* bih  = (const float*)d_in[6];
    const float* bhh  = (const float*)d_in[7];
    const float* fc1w = (const float*)d_in[8];
    const float* fc1b = (const float*)d_in[9];
    const float* fc2w = (const float*)d_in[10];
    const float* fc2b = (const float*)d_in[11];
    float* out = (float*)d_out;

    // ---- workspace layout ----
    float* h       = (float*)d_ws;               // 3.2M f
    float* bias4   = h + N_NODES * D1;           // 256 f
    int* deg       = (int*)(bias4 + 256);        // N_NODES
    u16* srcidx    = (u16*)(deg + N_NODES);      // N_NODES*CAP u16 = 6.4 MB
    size_t soff = ((size_t)(srcidx + N_NODES * CAP) + 15) & ~(size_t)15;
    u16* m16    = (u16*)soff;                    // 3.2M u16
    short* hhi  = (short*)(m16 + N_NODES * D1);  // 3.2M
    short* hlo  = hhi + N_NODES * D1;
    short* aghi = hlo + N_NODES * D1;
    short* aglo = aghi + N_NODES * D1;
    short* Bh   = aglo + N_NODES * D1;           // 32768
    short* Bl   = Bh + 32768;

    hipMemsetAsync(deg, 0, N_NODES * sizeof(int), stream);
    // interleaved fused: 313 groups x (10 fill + 3 other) = 4069 blocks
    fused_head_kernel<<<313 * 13, 256, 0, stream>>>(
        ei, deg, srcidx, x, W, wih, whh, bih, bhh, Bh, Bl, bias4, m16);

    // layer 0
    agg_kernel<<<N_NODES / 4, 256, 0, stream>>>(m16, deg, srcidx, aghi, aglo);
    gru_mfma<true, false><<<GRB, 256, 0, stream>>>(aghi, aglo, hhi, hlo, Bh, Bl, bias4, x, h);
    // layer 1
    mm_mfma<<<GB, 256, 0, stream>>>(hhi, hlo, W + 4096, m16);
    agg_kernel<<<N_NODES / 4, 256, 0, stream>>>(m16, deg, srcidx, aghi, aglo);
    gru_mfma<false, true><<<GRB, 256, 0, stream>>>(aghi, aglo, hhi, hlo, Bh, Bl, bias4, h, h);

    poolhead_kernel<<<N_GRAPHS, 256, 0, stream>>>(h, batch, fc1w, fc1b, fc2w, fc2b, out);
}

// Round 15
// 284.210 us; speedup vs baseline: 1.0917x; 1.0917x over previous
//
#include <hip/hip_runtime.h>

#define N_NODES 50000
#define N_EDGES 800000
#define D1 64
#define D2 32
#define N_CLASSES 6
#define N_GRAPHS 128
#define CAP 64       // per-node src bucket capacity == wave size; deg max ~45 << 64
#define GB 782       // ceil(50000/64) for 16x16 mm tiles
#define GRB 391      // ceil(50000/128) for 32-row-per-wave gru blocks
#define NFB 3125     // N_EDGES/256 fill blocks

typedef unsigned short u16;
typedef unsigned int u32;
typedef __attribute__((ext_vector_type(8))) short bf16x8;
typedef __attribute__((ext_vector_type(4))) float f32x4;
typedef __attribute__((ext_vector_type(16))) float f32x16;

__device__ __forceinline__ float bf2f(u16 b) {
    u32 u = ((u32)b) << 16;
    float f;
    __builtin_memcpy(&f, &u, 4);
    return f;
}
__device__ __forceinline__ u16 f2bf(float f) {
    u32 u;
    __builtin_memcpy(&u, &f, 4);
    u32 r = (u + 0x7fffu + ((u >> 16) & 1u)) >> 16;
    return (u16)r;
}
__device__ __forceinline__ void split8(const float* v, bf16x8& hi, bf16x8& lo) {
#pragma unroll
    for (int j = 0; j < 8; ++j) {
        u16 h = f2bf(v[j]);
        hi[j] = (short)h;
        lo[j] = (short)f2bf(v[j] - bf2f(h));
    }
}
__device__ __forceinline__ void round8(const float* v, bf16x8& b) {
#pragma unroll
    for (int j = 0; j < 8; ++j) b[j] = (short)f2bf(v[j]);
}
__device__ __forceinline__ float sigmoidf_(float x) {
    return 1.0f / (1.0f + __expf(-x));
}
__device__ __forceinline__ float tanhf_(float x) {
    return 1.0f - 2.0f / (__expf(2.0f * x) + 1.0f);
}

// ===== fused: fill + pack + mm L0, interleaved in block-index space =====
// period-13 groups: 10 fill + 3 other (r12 lesson: consecutive ranges queue serially).
// B packed (single bf16) for 32x32x16 fragments: idx=(kt*8+nt)*512+lane*8+j,
//   value=Blog[k=kt*16+(lane>>5)*8+j][n=nt*32+(lane&31)], kt,nt in 0..7.
__global__ __launch_bounds__(256) void fused_head_kernel(
        const int* __restrict__ ei, int* __restrict__ deg, u16* __restrict__ srcidx,
        const float* __restrict__ x, const float* __restrict__ W,
        const float* __restrict__ wih, const float* __restrict__ whh,
        const float* __restrict__ bih, const float* __restrict__ bhh,
        short* __restrict__ Bh, float* __restrict__ bias4,
        u16* __restrict__ m16) {
    int b = blockIdx.x;
    int tid = threadIdx.x;
    int grp = b / 13, rem = b % 13;
    if (rem < 10) {
        // ---- bucketed fill: one edge per thread (deg pre-zeroed via memset) ----
        int fb = grp * 10 + rem;
        if (fb >= NFB) return;
        int e = fb * 256 + tid;
        int d = ei[N_EDGES + e];
        int s = ei[e];
        int p = atomicAdd(&deg[d], 1);
        if (p < CAP) srcidx[d * CAP + p] = (u16)s;
        return;
    }
    int ob = grp * 3 + (rem - 10);  // 128 pack + 1 bias + 782 mm = 911 used
    if (ob < 128) {
        // ---- pack GRU B (single bf16) in 32x32x16 fragment order ----
        int idx = ob * 256 + tid;
        int j = idx & 7;
        int lane = (idx >> 3) & 63;
        int nt = (idx >> 9) & 7;
        int kt = idx >> 12;
        int k = kt * 16 + (lane >> 5) * 8 + j;
        int n = nt * 32 + (lane & 31);
        int g = n >> 6, d = n & 63;
        float v;
        if (g == 0)      v = (k < 64) ? wih[d * 64 + k] : whh[d * 64 + (k - 64)];
        else if (g == 1) v = (k < 64) ? wih[(64 + d) * 64 + k] : whh[(64 + d) * 64 + (k - 64)];
        else if (g == 2) v = (k < 64) ? wih[(128 + d) * 64 + k] : 0.f;
        else             v = (k < 64) ? 0.f : whh[(128 + d) * 64 + (k - 64)];
        Bh[idx] = (short)f2bf(v);
    } else if (ob == 128) {
        int j = tid;
        if (j < 64) {
            bias4[j] = bih[j] + bhh[j];
            bias4[64 + j] = bih[64 + j] + bhh[64 + j];
            bias4[128 + j] = bih[128 + j];
            bias4[192 + j] = bhh[128 + j];
        }
    } else if (ob < 129 + GB) {
        // ---- mm L0: m = x @ W0 (A split bf16, W single bf16; out m16 bf16) ----
        int lane = tid & 63;
        int wv = tid >> 6;
        int node0 = (ob - 129) * 64 + wv * 16;
        if (node0 >= N_NODES) return;
        int c0 = lane & 15, qr = lane >> 4;
        f32x4 acc[4];
#pragma unroll
        for (int nt = 0; nt < 4; ++nt) acc[nt] = (f32x4){0.f, 0.f, 0.f, 0.f};
#pragma unroll
        for (int kt = 0; kt < 2; ++kt) {
            int aoff = (node0 + c0) * 64 + kt * 32 + qr * 8;
            float tmp[8];
#pragma unroll
            for (int j = 0; j < 8; ++j) tmp[j] = x[aoff + j];
            bf16x8 ah, al;
            split8(tmp, ah, al);
            int k0 = kt * 32 + qr * 8;
#pragma unroll
            for (int nt = 0; nt < 4; ++nt) {
                int n = nt * 16 + c0;
                float wt[8];
#pragma unroll
                for (int j = 0; j < 8; ++j) wt[j] = W[(k0 + j) * 64 + n];
                bf16x8 bb;
                round8(wt, bb);
                acc[nt] = __builtin_amdgcn_mfma_f32_16x16x32_bf16(ah, bb, acc[nt], 0, 0, 0);
                acc[nt] = __builtin_amdgcn_mfma_f32_16x16x32_bf16(al, bb, acc[nt], 0, 0, 0);
            }
        }
#pragma unroll
        for (int nt = 0; nt < 4; ++nt)
#pragma unroll
            for (int r = 0; r < 4; ++r)
                m16[(node0 + qr * 4 + r) * 64 + nt * 16 + c0] = f2bf(acc[nt][r]);
    }
}

// ===== mm L1: m = h @ W1 (16x16), A from hhi/hlo, W single bf16 =====
__global__ __launch_bounds__(256) void mm_mfma(const short* __restrict__ Ahi,
                                               const short* __restrict__ Alo,
                                               const float* __restrict__ Wf,
                                               u16* __restrict__ m16) {
    int lane = threadIdx.x & 63;
    int wv = threadIdx.x >> 6;
    int node0 = blockIdx.x * 64 + wv * 16;
    if (node0 >= N_NODES) return;
    int c0 = lane & 15, qr = lane >> 4;
    f32x4 acc[4];
#pragma unroll
    for (int nt = 0; nt < 4; ++nt) acc[nt] = (f32x4){0.f, 0.f, 0.f, 0.f};
#pragma unroll
    for (int kt = 0; kt < 2; ++kt) {
        int aoff = (node0 + c0) * 64 + kt * 32 + qr * 8;
        bf16x8 ah = *(const bf16x8*)(Ahi + aoff);
        bf16x8 al = *(const bf16x8*)(Alo + aoff);
        int k0 = kt * 32 + qr * 8;
#pragma unroll
        for (int nt = 0; nt < 4; ++nt) {
            int n = nt * 16 + c0;
            float wt[8];
#pragma unroll
            for (int j = 0; j < 8; ++j) wt[j] = Wf[(k0 + j) * 64 + n];
            bf16x8 bb;
            round8(wt, bb);
            acc[nt] = __builtin_amdgcn_mfma_f32_16x16x32_bf16(ah, bb, acc[nt], 0, 0, 0);
            acc[nt] = __builtin_amdgcn_mfma_f32_16x16x32_bf16(al, bb, acc[nt], 0, 0, 0);
        }
    }
#pragma unroll
    for (int nt = 0; nt < 4; ++nt)
#pragma unroll
        for (int r = 0; r < 4; ++r)
            m16[(node0 + qr * 4 + r) * 64 + nt * 16 + c0] = f2bf(acc[nt][r]);
}

// ===== agg: wave per node; half-wave dword gather =====
__global__ __launch_bounds__(256) void agg_kernel(const u16* __restrict__ m16,
                                                  const int* __restrict__ deg,
                                                  const u16* __restrict__ srcidx,
                                                  short* __restrict__ aghi,
                                                  short* __restrict__ aglo) {
    int lane = threadIdx.x & 63;
    int wv = threadIdx.x >> 6;
    int node = blockIdx.x * 4 + wv;  // grid exact: 50000/4
    int cnt = __builtin_amdgcn_readfirstlane(deg[node]);
    cnt = cnt < CAP ? cnt : CAP;
    int bv = (int)srcidx[node * CAP + lane];
    int half = lane >> 5;
    int l = lane & 31;
    const u32* m32 = (const u32*)m16;
    float a0 = 0.f, a1 = 0.f;
    int k = half;
    for (; k + 6 < cnt; k += 8) {
        int s0 = __shfl(bv, k);
        int s1 = __shfl(bv, k + 2);
        int s2 = __shfl(bv, k + 4);
        int s3 = __shfl(bv, k + 6);
        u32 d0 = m32[s0 * 32 + l];
        u32 d1 = m32[s1 * 32 + l];
        u32 d2 = m32[s2 * 32 + l];
        u32 d3 = m32[s3 * 32 + l];
        a0 += bf2f((u16)d0) + bf2f((u16)d1) + bf2f((u16)d2) + bf2f((u16)d3);
        a1 += bf2f((u16)(d0 >> 16)) + bf2f((u16)(d1 >> 16)) +
              bf2f((u16)(d2 >> 16)) + bf2f((u16)(d3 >> 16));
    }
    for (; k < cnt; k += 2) {
        int s = __shfl(bv, k);
        u32 d = m32[s * 32 + l];
        a0 += bf2f((u16)d);
        a1 += bf2f((u16)(d >> 16));
    }
    a0 += __shfl_xor(a0, 32);
    a1 += __shfl_xor(a1, 32);
    if (half == 0) {
        u16 h0 = f2bf(a0), h1 = f2bf(a1);
        u16 g0 = f2bf(a0 - bf2f(h0)), g1 = f2bf(a1 - bf2f(h1));
        ((u32*)aghi)[node * 32 + l] = (u32)h0 | ((u32)h1 << 16);
        ((u32*)aglo)[node * 32 + l] = (u32)g0 | ((u32)g1 << 16);
    }
}

// ===== GRU on 32x32x16 MFMA: wave = 32 rows; A split bf16, B single bf16 (64
// L2 loads/wave, 2 MFMAs/tile); no LDS, no barriers. =====
// A layout: m=lane&31, k=(lane>>5)*8+j. C/D: col=lane&31, row=(reg&3)+8*(reg>>2)+4*(lane>>5).
template <bool L0, bool LAST>
__global__ __launch_bounds__(256) void gru_mfma(const short* __restrict__ aghi,
                                                const short* __restrict__ aglo,
                                                short* hhi, short* hlo,
                                                const short* __restrict__ Bh,
                                                const float* __restrict__ bias4,
                                                const float* __restrict__ hin,  // x (L0) or h f32
                                                float* __restrict__ hout) {
    int tid = threadIdx.x;
    int lane = tid & 63;
    int wv = tid >> 6;
    int node0 = blockIdx.x * 128 + wv * 32;
    if (node0 >= N_NODES) return;
    int c = lane & 31, half = lane >> 5;
    int rowA = node0 + c;
    if (rowA > N_NODES - 1) rowA = N_NODES - 1;

    f32x16 acc[8];
#pragma unroll
    for (int nt = 0; nt < 8; ++nt)
#pragma unroll
        for (int i = 0; i < 16; ++i) acc[nt][i] = 0.f;

#pragma unroll
    for (int kt = 0; kt < 8; ++kt) {
        bf16x8 ah, al;
        int aoff = rowA * 64 + (kt & 3) * 16 + half * 8;
        if (kt < 4) {
            ah = *(const bf16x8*)(aghi + aoff);
            al = *(const bf16x8*)(aglo + aoff);
        } else if (L0) {  // h half = x, split in-register
            float tmp[8];
#pragma unroll
            for (int j = 0; j < 8; ++j) tmp[j] = hin[aoff + j];
            split8(tmp, ah, al);
        } else {
            ah = *(const bf16x8*)(hhi + aoff);
            al = *(const bf16x8*)(hlo + aoff);
        }
#pragma unroll
        for (int nt = 0; nt < 8; ++nt) {
            int boff = (kt * 8 + nt) * 512 + lane * 8;
            bf16x8 bb = *(const bf16x8*)(Bh + boff);
            acc[nt] = __builtin_amdgcn_mfma_f32_32x32x16_bf16(ah, bb, acc[nt], 0, 0, 0);
            acc[nt] = __builtin_amdgcn_mfma_f32_32x32x16_bf16(al, bb, acc[nt], 0, 0, 0);
        }
    }

    // gates: col j=jt*32+c lives in nt {jt, 2+jt, 4+jt, 6+jt} (r, z, i_n, h_n)
#pragma unroll
    for (int reg = 0; reg < 16; ++reg) {
        int row = node0 + (reg & 3) + 8 * (reg >> 2) + 4 * half;
        if (row >= N_NODES) continue;
#pragma unroll
        for (int jt = 0; jt < 2; ++jt) {
            int j = jt * 32 + c;
            float rr = sigmoidf_(acc[jt][reg] + bias4[j]);
            float zz = sigmoidf_(acc[2 + jt][reg] + bias4[64 + j]);
            float nn = tanhf_(acc[4 + jt][reg] + bias4[128 + j] +
                              rr * (acc[6 + jt][reg] + bias4[192 + j]));
            float ho = hin[row * 64 + j];
            float v = (1.f - zz) * nn + zz * ho;
            hout[row * 64 + j] = v;
            if (!LAST) {
                u16 hi = f2bf(v);
                hhi[row * 64 + j] = (short)hi;
                hlo[row * 64 + j] = (short)f2bf(v - bf2f(hi));
            }
        }
    }
}

// ===== fused relu + segment-mean pool + fc1/relu/fc2/log_softmax; block per graph =====
__global__ __launch_bounds__(256) void poolhead_kernel(const float* __restrict__ h,
                                                       const int* __restrict__ batch,
                                                       const float* __restrict__ fc1w,
                                                       const float* __restrict__ fc1b,
                                                       const float* __restrict__ fc2w,
                                                       const float* __restrict__ fc2b,
                                                       float* __restrict__ out) {
    int g = blockIdx.x;
    int tid = threadIdx.x, lane = tid & 63, wv = tid >> 6;
    int lo, hi;
    {
        int a = 0, b = N_NODES;
        while (a < b) { int mid = (a + b) >> 1; if (batch[mid] < g) a = mid + 1; else b = mid; }
        lo = a;
    }
    {
        int a = lo, b = N_NODES;
        while (a < b) { int mid = (a + b) >> 1; if (batch[mid] < g + 1) a = mid + 1; else b = mid; }
        hi = a;
    }
    float acc = 0.f;
    for (int n = lo + wv; n < hi; n += 4) acc += fmaxf(h[n * 64 + lane], 0.f);
    __shared__ float red[4][64];
    __shared__ float pv[64];
    __shared__ float s1[32];
    __shared__ float s2[6];
    red[wv][lane] = acc;
    __syncthreads();
    if (tid < 64)
        pv[tid] = (red[0][tid] + red[1][tid] + red[2][tid] + red[3][tid]) /
                  fmaxf((float)(hi - lo), 1.f);
    __syncthreads();
    if (tid < 32) {
        float a2 = fc1b[tid];
#pragma unroll
        for (int j = 0; j < 64; ++j) a2 = fmaf(pv[j], fc1w[tid * 64 + j], a2);
        s1[tid] = fmaxf(a2, 0.f);
    }
    __syncthreads();
    if (tid < 6) {
        float a2 = fc2b[tid];
#pragma unroll
        for (int j = 0; j < 32; ++j) a2 = fmaf(s1[j], fc2w[tid * 32 + j], a2);
        s2[tid] = a2;
    }
    __syncthreads();
    if (tid == 0) {
        float mx = s2[0];
#pragma unroll
        for (int c = 1; c < 6; ++c) mx = fmaxf(mx, s2[c]);
        float se = 0.f;
#pragma unroll
        for (int c = 0; c < 6; ++c) se += __expf(s2[c] - mx);
        float lse = mx + __logf(se);
#pragma unroll
        for (int c = 0; c < 6; ++c) out[g * 6 + c] = s2[c] - lse;
    }
}

extern "C" void kernel_launch(void* const* d_in, const int* in_sizes, int n_in,
                              void* d_out, int out_size, void* d_ws, size_t ws_size,
                              hipStream_t stream) {
    const float* x    = (const float*)d_in[0];
    const int* ei     = (const int*)d_in[1];
    const int* batch  = (const int*)d_in[2];
    const float* W    = (const float*)d_in[3];
    const float* wih  = (const float*)d_in[4];
    const float* whh  = (const float*)d_in[5];
    const float* bih  = (const float*)d_in[6];
    const float* bhh  = (const float*)d_in[7];
    const float* fc1w = (const float*)d_in[8];
    const float* fc1b = (const float*)d_in[9];
    const float* fc2w = (const float*)d_in[10];
    const float* fc2b = (const float*)d_in[11];
    float* out = (float*)d_out;

    // ---- workspace layout ----
    float* h       = (float*)d_ws;               // 3.2M f
    float* bias4   = h + N_NODES * D1;           // 256 f
    int* deg       = (int*)(bias4 + 256);        // N_NODES
    u16* srcidx    = (u16*)(deg + N_NODES);      // N_NODES*CAP u16 = 6.4 MB
    size_t soff = ((size_t)(srcidx + N_NODES * CAP) + 15) & ~(size_t)15;
    u16* m16    = (u16*)soff;                    // 3.2M u16
    short* hhi  = (short*)(m16 + N_NODES * D1);  // 3.2M
    short* hlo  = hhi + N_NODES * D1;
    short* aghi = hlo + N_NODES * D1;
    short* aglo = aghi + N_NODES * D1;
    short* Bh   = aglo + N_NODES * D1;           // 32768

    hipMemsetAsync(deg, 0, N_NODES * sizeof(int), stream);
    // interleaved fused: 313 groups x (10 fill + 3 other) = 4069 blocks
    fused_head_kernel<<<313 * 13, 256, 0, stream>>>(
        ei, deg, srcidx, x, W, wih, whh, bih, bhh, Bh, bias4, m16);

    // layer 0
    agg_kernel<<<N_NODES / 4, 256, 0, stream>>>(m16, deg, srcidx, aghi, aglo);
    gru_mfma<true, false><<<GRB, 256, 0, stream>>>(aghi, aglo, hhi, hlo, Bh, bias4, x, h);
    // layer 1
    mm_mfma<<<GB, 256, 0, stream>>>(hhi, hlo, W + 4096, m16);
    agg_kernel<<<N_NODES / 4, 256, 0, stream>>>(m16, deg, srcidx, aghi, aglo);
    gru_mfma<false, true><<<GRB, 256, 0, stream>>>(aghi, aglo, hhi, hlo, Bh, bias4, h, h);

    poolhead_kernel<<<N_GRAPHS, 256, 0, stream>>>(h, batch, fc1w, fc1b, fc2w, fc2b, out);
}

// Round 16
// 280.458 us; speedup vs baseline: 1.1063x; 1.0134x over previous
//
#include <hip/hip_runtime.h>

#define N_NODES 50000
#define N_EDGES 800000
#define D1 64
#define D2 32
#define N_CLASSES 6
#define N_GRAPHS 128
#define CAP 64       // per-node src bucket capacity == wave size; deg max ~45 << 64
#define GB 782       // ceil(50000/64) for 16x16 mm tiles (mm L0 in fused kernel)
#define GRB 391      // ceil(50000/128) for 32-row-per-wave gru blocks
#define NFB 3125     // N_EDGES/256 fill blocks

typedef unsigned short u16;
typedef unsigned int u32;
typedef __attribute__((ext_vector_type(8))) short bf16x8;
typedef __attribute__((ext_vector_type(4))) float f32x4;
typedef __attribute__((ext_vector_type(16))) float f32x16;

__device__ __forceinline__ float bf2f(u16 b) {
    u32 u = ((u32)b) << 16;
    float f;
    __builtin_memcpy(&f, &u, 4);
    return f;
}
__device__ __forceinline__ u16 f2bf(float f) {
    u32 u;
    __builtin_memcpy(&u, &f, 4);
    u32 r = (u + 0x7fffu + ((u >> 16) & 1u)) >> 16;
    return (u16)r;
}
__device__ __forceinline__ void split8(const float* v, bf16x8& hi, bf16x8& lo) {
#pragma unroll
    for (int j = 0; j < 8; ++j) {
        u16 h = f2bf(v[j]);
        hi[j] = (short)h;
        lo[j] = (short)f2bf(v[j] - bf2f(h));
    }
}
__device__ __forceinline__ void round8(const float* v, bf16x8& b) {
#pragma unroll
    for (int j = 0; j < 8; ++j) b[j] = (short)f2bf(v[j]);
}
__device__ __forceinline__ float sigmoidf_(float x) {
    return 1.0f / (1.0f + __expf(-x));
}
__device__ __forceinline__ float tanhf_(float x) {
    return 1.0f - 2.0f / (__expf(2.0f * x) + 1.0f);
}

// ===== fused: fill + pack + mm L0, interleaved in block-index space =====
// period-13 groups: 10 fill + 3 other (r12 lesson: consecutive ranges queue serially).
// B packed (single bf16) for 32x32x16 fragments: idx=(kt*8+nt)*512+lane*8+j,
//   value=Blog[k=kt*16+(lane>>5)*8+j][n=nt*32+(lane&31)], kt,nt in 0..7.
__global__ __launch_bounds__(256) void fused_head_kernel(
        const int* __restrict__ ei, int* __restrict__ deg, u16* __restrict__ srcidx,
        const float* __restrict__ x, const float* __restrict__ W,
        const float* __restrict__ wih, const float* __restrict__ whh,
        const float* __restrict__ bih, const float* __restrict__ bhh,
        short* __restrict__ Bh, float* __restrict__ bias4,
        u16* __restrict__ m16) {
    int b = blockIdx.x;
    int tid = threadIdx.x;
    int grp = b / 13, rem = b % 13;
    if (rem < 10) {
        // ---- bucketed fill: one edge per thread (deg pre-zeroed via memset) ----
        int fb = grp * 10 + rem;
        if (fb >= NFB) return;
        int e = fb * 256 + tid;
        int d = ei[N_EDGES + e];
        int s = ei[e];
        int p = atomicAdd(&deg[d], 1);
        if (p < CAP) srcidx[d * CAP + p] = (u16)s;
        return;
    }
    int ob = grp * 3 + (rem - 10);  // 128 pack + 1 bias + 782 mm = 911 used
    if (ob < 128) {
        // ---- pack GRU B (single bf16) in 32x32x16 fragment order ----
        int idx = ob * 256 + tid;
        int j = idx & 7;
        int lane = (idx >> 3) & 63;
        int nt = (idx >> 9) & 7;
        int kt = idx >> 12;
        int k = kt * 16 + (lane >> 5) * 8 + j;
        int n = nt * 32 + (lane & 31);
        int g = n >> 6, d = n & 63;
        float v;
        if (g == 0)      v = (k < 64) ? wih[d * 64 + k] : whh[d * 64 + (k - 64)];
        else if (g == 1) v = (k < 64) ? wih[(64 + d) * 64 + k] : whh[(64 + d) * 64 + (k - 64)];
        else if (g == 2) v = (k < 64) ? wih[(128 + d) * 64 + k] : 0.f;
        else             v = (k < 64) ? 0.f : whh[(128 + d) * 64 + (k - 64)];
        Bh[idx] = (short)f2bf(v);
    } else if (ob == 128) {
        int j = tid;
        if (j < 64) {
            bias4[j] = bih[j] + bhh[j];
            bias4[64 + j] = bih[64 + j] + bhh[64 + j];
            bias4[128 + j] = bih[128 + j];
            bias4[192 + j] = bhh[128 + j];
        }
    } else if (ob < 129 + GB) {
        // ---- mm L0: m = x @ W0 (A split bf16, W single bf16; out m16 bf16) ----
        int lane = tid & 63;
        int wv = tid >> 6;
        int node0 = (ob - 129) * 64 + wv * 16;
        if (node0 >= N_NODES) return;
        int c0 = lane & 15, qr = lane >> 4;
        f32x4 acc[4];
#pragma unroll
        for (int nt = 0; nt < 4; ++nt) acc[nt] = (f32x4){0.f, 0.f, 0.f, 0.f};
#pragma unroll
        for (int kt = 0; kt < 2; ++kt) {
            int aoff = (node0 + c0) * 64 + kt * 32 + qr * 8;
            float tmp[8];
#pragma unroll
            for (int j = 0; j < 8; ++j) tmp[j] = x[aoff + j];
            bf16x8 ah, al;
            split8(tmp, ah, al);
            int k0 = kt * 32 + qr * 8;
#pragma unroll
            for (int nt = 0; nt < 4; ++nt) {
                int n = nt * 16 + c0;
                float wt[8];
#pragma unroll
                for (int j = 0; j < 8; ++j) wt[j] = W[(k0 + j) * 64 + n];
                bf16x8 bb;
                round8(wt, bb);
                acc[nt] = __builtin_amdgcn_mfma_f32_16x16x32_bf16(ah, bb, acc[nt], 0, 0, 0);
                acc[nt] = __builtin_amdgcn_mfma_f32_16x16x32_bf16(al, bb, acc[nt], 0, 0, 0);
            }
        }
#pragma unroll
        for (int nt = 0; nt < 4; ++nt)
#pragma unroll
            for (int r = 0; r < 4; ++r)
                m16[(node0 + qr * 4 + r) * 64 + nt * 16 + c0] = f2bf(acc[nt][r]);
    }
}

// ===== agg: wave per node; half-wave dword gather =====
__global__ __launch_bounds__(256) void agg_kernel(const u16* __restrict__ m16,
                                                  const int* __restrict__ deg,
                                                  const u16* __restrict__ srcidx,
                                                  short* __restrict__ aghi,
                                                  short* __restrict__ aglo) {
    int lane = threadIdx.x & 63;
    int wv = threadIdx.x >> 6;
    int node = blockIdx.x * 4 + wv;  // grid exact: 50000/4
    int cnt = __builtin_amdgcn_readfirstlane(deg[node]);
    cnt = cnt < CAP ? cnt : CAP;
    int bv = (int)srcidx[node * CAP + lane];
    int half = lane >> 5;
    int l = lane & 31;
    const u32* m32 = (const u32*)m16;
    float a0 = 0.f, a1 = 0.f;
    int k = half;
    for (; k + 6 < cnt; k += 8) {
        int s0 = __shfl(bv, k);
        int s1 = __shfl(bv, k + 2);
        int s2 = __shfl(bv, k + 4);
        int s3 = __shfl(bv, k + 6);
        u32 d0 = m32[s0 * 32 + l];
        u32 d1 = m32[s1 * 32 + l];
        u32 d2 = m32[s2 * 32 + l];
        u32 d3 = m32[s3 * 32 + l];
        a0 += bf2f((u16)d0) + bf2f((u16)d1) + bf2f((u16)d2) + bf2f((u16)d3);
        a1 += bf2f((u16)(d0 >> 16)) + bf2f((u16)(d1 >> 16)) +
              bf2f((u16)(d2 >> 16)) + bf2f((u16)(d3 >> 16));
    }
    for (; k < cnt; k += 2) {
        int s = __shfl(bv, k);
        u32 d = m32[s * 32 + l];
        a0 += bf2f((u16)d);
        a1 += bf2f((u16)(d >> 16));
    }
    a0 += __shfl_xor(a0, 32);
    a1 += __shfl_xor(a1, 32);
    if (half == 0) {
        u16 h0 = f2bf(a0), h1 = f2bf(a1);
        u16 g0 = f2bf(a0 - bf2f(h0)), g1 = f2bf(a1 - bf2f(h1));
        ((u32*)aghi)[node * 32 + l] = (u32)h0 | ((u32)h1 << 16);
        ((u32*)aglo)[node * 32 + l] = (u32)g0 | ((u32)g1 << 16);
    }
}

// ===== GRU on 32x32x16 MFMA: wave = 32 rows; A split bf16, B single bf16;
// no barriers (wave-granular). DO_MM: fused next-layer mm via wave-local
// stride-65 LDS tile — conflict-free (every bank exactly 2-way; r13's 16-row
// variant had 8-way conflicts, 32-row stride-65 is clean). =====
// A layout: m=lane&31, k=(lane>>5)*8+j. C/D: col=lane&31, row=(reg&3)+8*(reg>>2)+4*(lane>>5).
template <bool L0, bool DO_MM, bool LAST>
__global__ __launch_bounds__(256) void gru_mfma(const short* __restrict__ aghi,
                                                const short* __restrict__ aglo,
                                                short* hhi, short* hlo,
                                                const short* __restrict__ Bh,
                                                const float* __restrict__ bias4,
                                                const float* __restrict__ hin,  // x (L0) or h f32
                                                float* __restrict__ hout,
                                                const float* __restrict__ Wnext,
                                                u16* __restrict__ m16) {
    __shared__ float tile[DO_MM ? 4 * 32 * 65 : 4];  // wave-local transpose tiles (33.3 KB)
    int tid = threadIdx.x;
    int lane = tid & 63;
    int wv = tid >> 6;
    int node0 = blockIdx.x * 128 + wv * 32;
    if (node0 >= N_NODES) return;
    int c = lane & 31, half = lane >> 5;
    int rowA = node0 + c;
    if (rowA > N_NODES - 1) rowA = N_NODES - 1;

    f32x16 acc[8];
#pragma unroll
    for (int nt = 0; nt < 8; ++nt)
#pragma unroll
        for (int i = 0; i < 16; ++i) acc[nt][i] = 0.f;

#pragma unroll
    for (int kt = 0; kt < 8; ++kt) {
        bf16x8 ah, al;
        int aoff = rowA * 64 + (kt & 3) * 16 + half * 8;
        if (kt < 4) {
            ah = *(const bf16x8*)(aghi + aoff);
            al = *(const bf16x8*)(aglo + aoff);
        } else if (L0) {  // h half = x, split in-register
            float tmp[8];
#pragma unroll
            for (int j = 0; j < 8; ++j) tmp[j] = hin[aoff + j];
            split8(tmp, ah, al);
        } else {
            ah = *(const bf16x8*)(hhi + aoff);
            al = *(const bf16x8*)(hlo + aoff);
        }
#pragma unroll
        for (int nt = 0; nt < 8; ++nt) {
            int boff = (kt * 8 + nt) * 512 + lane * 8;
            bf16x8 bb = *(const bf16x8*)(Bh + boff);
            acc[nt] = __builtin_amdgcn_mfma_f32_32x32x16_bf16(ah, bb, acc[nt], 0, 0, 0);
            acc[nt] = __builtin_amdgcn_mfma_f32_32x32x16_bf16(al, bb, acc[nt], 0, 0, 0);
        }
    }

    float* myTile = tile + (DO_MM ? wv * 32 * 65 : 0);

    // gates: col j=jt*32+c lives in nt {jt, 2+jt, 4+jt, 6+jt} (r, z, i_n, h_n)
#pragma unroll
    for (int reg = 0; reg < 16; ++reg) {
        int R = (reg & 3) + 8 * (reg >> 2) + 4 * half;  // local row 0..31
        int row = node0 + R;
        bool ok = row < N_NODES;
        int rrow = ok ? row : N_NODES - 1;  // clamp reads; writes guarded
#pragma unroll
        for (int jt = 0; jt < 2; ++jt) {
            int j = jt * 32 + c;
            float rr = sigmoidf_(acc[jt][reg] + bias4[j]);
            float zz = sigmoidf_(acc[2 + jt][reg] + bias4[64 + j]);
            float nn = tanhf_(acc[4 + jt][reg] + bias4[128 + j] +
                              rr * (acc[6 + jt][reg] + bias4[192 + j]));
            float ho = hin[rrow * 64 + j];
            float v = (1.f - zz) * nn + zz * ho;
            if (ok) {
                hout[row * 64 + j] = v;
                if (!LAST) {
                    u16 hi = f2bf(v);
                    hhi[row * 64 + j] = (short)hi;
                    hlo[row * 64 + j] = (short)f2bf(v - bf2f(hi));
                }
            }
            if (DO_MM) myTile[R * 65 + j] = v;  // bank (R+c)%32: 2-way, free
        }
    }

    if (DO_MM) {
        // mm next layer: m16[row] = h[row] @ Wnext (A bf16, W bf16 — m16 is
        // bf16-rounded anyway). A from wave-local tile, row = lane&31.
        f32x16 macc[2];
#pragma unroll
        for (int nt = 0; nt < 2; ++nt)
#pragma unroll
            for (int i = 0; i < 16; ++i) macc[nt][i] = 0.f;
#pragma unroll
        for (int kt = 0; kt < 4; ++kt) {
            int k0 = kt * 16 + half * 8;
            float tmp[8];
#pragma unroll
            for (int j = 0; j < 8; ++j) tmp[j] = myTile[c * 65 + k0 + j];  // 2-way, free
            bf16x8 aa;
            round8(tmp, aa);
#pragma unroll
            for (int nt = 0; nt < 2; ++nt) {
                float wt[8];
#pragma unroll
                for (int j = 0; j < 8; ++j) wt[j] = Wnext[(k0 + j) * 64 + nt * 32 + c];
                bf16x8 bb;
                round8(wt, bb);
                macc[nt] = __builtin_amdgcn_mfma_f32_32x32x16_bf16(aa, bb, macc[nt], 0, 0, 0);
            }
        }
#pragma unroll
        for (int nt = 0; nt < 2; ++nt)
#pragma unroll
            for (int reg = 0; reg < 16; ++reg) {
                int row = node0 + (reg & 3) + 8 * (reg >> 2) + 4 * half;
                if (row < N_NODES)
                    m16[row * 64 + nt * 32 + c] = f2bf(macc[nt][reg]);
            }
    }
}

// ===== fused relu + segment-mean pool + fc1/relu/fc2/log_softmax; block per graph =====
__global__ __launch_bounds__(256) void poolhead_kernel(const float* __restrict__ h,
                                                       const int* __restrict__ batch,
                                                       const float* __restrict__ fc1w,
                                                       const float* __restrict__ fc1b,
                                                       const float* __restrict__ fc2w,
                                                       const float* __restrict__ fc2b,
                                                       float* __restrict__ out) {
    int g = blockIdx.x;
    int tid = threadIdx.x, lane = tid & 63, wv = tid >> 6;
    int lo, hi;
    {
        int a = 0, b = N_NODES;
        while (a < b) { int mid = (a + b) >> 1; if (batch[mid] < g) a = mid + 1; else b = mid; }
        lo = a;
    }
    {
        int a = lo, b = N_NODES;
        while (a < b) { int mid = (a + b) >> 1; if (batch[mid] < g + 1) a = mid + 1; else b = mid; }
        hi = a;
    }
    float acc = 0.f;
    for (int n = lo + wv; n < hi; n += 4) acc += fmaxf(h[n * 64 + lane], 0.f);
    __shared__ float red[4][64];
    __shared__ float pv[64];
    __shared__ float s1[32];
    __shared__ float s2[6];
    red[wv][lane] = acc;
    __syncthreads();
    if (tid < 64)
        pv[tid] = (red[0][tid] + red[1][tid] + red[2][tid] + red[3][tid]) /
                  fmaxf((float)(hi - lo), 1.f);
    __syncthreads();
    if (tid < 32) {
        float a2 = fc1b[tid];
#pragma unroll
        for (int j = 0; j < 64; ++j) a2 = fmaf(pv[j], fc1w[tid * 64 + j], a2);
        s1[tid] = fmaxf(a2, 0.f);
    }
    __syncthreads();
    if (tid < 6) {
        float a2 = fc2b[tid];
#pragma unroll
        for (int j = 0; j < 32; ++j) a2 = fmaf(s1[j], fc2w[tid * 32 + j], a2);
        s2[tid] = a2;
    }
    __syncthreads();
    if (tid == 0) {
        float mx = s2[0];
#pragma unroll
        for (int c = 1; c < 6; ++c) mx = fmaxf(mx, s2[c]);
        float se = 0.f;
#pragma unroll
        for (int c = 0; c < 6; ++c) se += __expf(s2[c] - mx);
        float lse = mx + __logf(se);
#pragma unroll
        for (int c = 0; c < 6; ++c) out[g * 6 + c] = s2[c] - lse;
    }
}

extern "C" void kernel_launch(void* const* d_in, const int* in_sizes, int n_in,
                              void* d_out, int out_size, void* d_ws, size_t ws_size,
                              hipStream_t stream) {
    const float* x    = (const float*)d_in[0];
    const int* ei     = (const int*)d_in[1];
    const int* batch  = (const int*)d_in[2];
    const float* W    = (const float*)d_in[3];
    const float* wih  = (const float*)d_in[4];
    const float* whh  = (const float*)d_in[5];
    const float* bih  = (const float*)d_in[6];
    const float* bhh  = (const float*)d_in[7];
    const float* fc1w = (const float*)d_in[8];
    const float* fc1b = (const float*)d_in[9];
    const float* fc2w = (const float*)d_in[10];
    const float* fc2b = (const float*)d_in[11];
    float* out = (float*)d_out;

    // ---- workspace layout ----
    float* h       = (float*)d_ws;               // 3.2M f
    float* bias4   = h + N_NODES * D1;           // 256 f
    int* deg       = (int*)(bias4 + 256);        // N_NODES
    u16* srcidx    = (u16*)(deg + N_NODES);      // N_NODES*CAP u16 = 6.4 MB
    size_t soff = ((size_t)(srcidx + N_NODES * CAP) + 15) & ~(size_t)15;
    u16* m16    = (u16*)soff;                    // 3.2M u16
    short* hhi  = (short*)(m16 + N_NODES * D1);  // 3.2M
    short* hlo  = hhi + N_NODES * D1;
    short* aghi = hlo + N_NODES * D1;
    short* aglo = aghi + N_NODES * D1;
    short* Bh   = aglo + N_NODES * D1;           // 32768

    hipMemsetAsync(deg, 0, N_NODES * sizeof(int), stream);
    // interleaved fused: 313 groups x (10 fill + 3 other) = 4069 blocks
    fused_head_kernel<<<313 * 13, 256, 0, stream>>>(
        ei, deg, srcidx, x, W, wih, whh, bih, bhh, Bh, bias4, m16);

    // layer 0: agg -> gru (+ fused mm of layer 1)
    agg_kernel<<<N_NODES / 4, 256, 0, stream>>>(m16, deg, srcidx, aghi, aglo);
    gru_mfma<true, true, false><<<GRB, 256, 0, stream>>>(
        aghi, aglo, hhi, hlo, Bh, bias4, x, h, W + 4096, m16);
    // layer 1: agg -> gru (last: no hhi/hlo, no mm)
    agg_kernel<<<N_NODES / 4, 256, 0, stream>>>(m16, deg, srcidx, aghi, aglo);
    gru_mfma<false, false, true><<<GRB, 256, 0, stream>>>(
        aghi, aglo, hhi, hlo, Bh, bias4, h, h, nullptr, nullptr);

    poolhead_kernel<<<N_GRAPHS, 256, 0, stream>>>(h, batch, fc1w, fc1b, fc2w, fc2b, out);
}